// Round 7
// baseline (336.512 us; speedup 1.0000x reference)
//
#include <hip/hip_runtime.h>
#include <hip/hip_bf16.h>

#define D_DIM 256
#define K_CODES 1024
#define HW 1024
#define N_VEC 32768
#define N_ELEM 8388608ull

typedef __attribute__((ext_vector_type(8))) short bf16x8;
typedef __attribute__((ext_vector_type(4))) float f32x4;

static __device__ __forceinline__ unsigned short f2bf(float x) {
    union { __hip_bfloat16 h; unsigned short u; } cvt;
    cvt.h = __float2bfloat16(x);
    return cvt.u;
}

// ---------------------------------------------------------------------------
// Kernel A (fused prep): codebook -> bf16 B-fragment order + codebook norms
// + zero counts/lossacc. 128 blocks x 256.
// ---------------------------------------------------------------------------
__global__ __launch_bounds__(256) void prep_kernel(const float* __restrict__ cb,
                                                   unsigned short* __restrict__ cbb,
                                                   float* __restrict__ cnorm,
                                                   int* __restrict__ counts,
                                                   float* __restrict__ lossacc) {
    int slot = blockIdx.x * 256 + threadIdx.x;  // 0 .. 32767
    {
        int lane = slot & 63;
        int dchunk = (slot >> 6) & 7;
        int ktile = slot >> 9;
        int code = ktile * 16 + (lane & 15);
        int d0 = dchunk * 32 + (lane >> 4) * 8;
        const float4* src = (const float4*)(cb + (size_t)code * D_DIM + d0);
        float4 v0 = src[0], v1 = src[1];
        int4 o;
        o.x = f2bf(v0.x) | ((unsigned)f2bf(v0.y) << 16);
        o.y = f2bf(v0.z) | ((unsigned)f2bf(v0.w) << 16);
        o.z = f2bf(v1.x) | ((unsigned)f2bf(v1.y) << 16);
        o.w = f2bf(v1.z) | ((unsigned)f2bf(v1.w) << 16);
        *(int4*)(cbb + (size_t)slot * 8) = o;
    }
    if (slot < 8192) {
        if (slot < K_CODES) counts[slot] = 0;
        if (slot == K_CODES) lossacc[0] = 0.f;
        int k = slot >> 3;
        int part = slot & 7;
        const float4* row = (const float4*)(cb + (size_t)k * D_DIM + part * 32);
        float s = 0.f;
#pragma unroll
        for (int i = 0; i < 8; i++) {
            float4 v = row[i];
            s = fmaf(v.x, v.x, s);
            s = fmaf(v.y, v.y, s);
            s = fmaf(v.z, v.z, s);
            s = fmaf(v.w, v.w, s);
        }
        s += __shfl_xor(s, 1);
        s += __shfl_xor(s, 2);
        s += __shfl_xor(s, 4);
        if (part == 0) cnorm[k] = s;
    }
}

// ---------------------------------------------------------------------------
// Kernel B: K-split argmin. Grid = 4 K-quarters x 256 n-blocks. Block = 256
// thr (4 waves) x 128 n x 256 codes. 8 double-buffered 16KB chunks (2 ktiles)
// via global_load_lds(16B). LDS 32.8KB + launch_bounds(256,3) => 3 blocks/CU
// (12 waves/CU) — 3x the TLP of R6's 1-block/CU mega (its 85%-idle cause).
// Writes per-n per-quarter (dist,k) partials; no atomics here.
// score = ||c||^2 - 2*z.c  (per-n ||z||^2 dropped; doesn't move argmin).
// ---------------------------------------------------------------------------
__global__ __launch_bounds__(256, 3) void argmin_part(const float* __restrict__ z,
                                                      const unsigned short* __restrict__ cbb,
                                                      const float* __restrict__ cnorm,
                                                      float* __restrict__ pd,
                                                      int* __restrict__ pk) {
    __shared__ __align__(16) unsigned short Bbuf[2][8192];  // 2 x 16 KB
    const int t = threadIdx.x;
    const int lane = t & 63;
    const int w = t >> 6;              // wave 0..3
    const int q = blockIdx.x & 3;      // K-quarter: codes [q*256, q*256+256)
    const int nb = blockIdx.x >> 2;    // n-block 0..255
    const int nt0 = nb * 8 + w * 2;    // wave owns ntiles nt0, nt0+1
    const unsigned short* cq = cbb + (size_t)q * 16 * 4096;  // 16 ktiles/quarter

    // ---- prologue: load + convert A fragments (2 ntiles x 8 dchunks) ----
    bf16x8 Ar[2][8];
    {
        const int row = lane & 15;
        const int dq = (lane >> 4) * 8;
#pragma unroll
        for (int nt = 0; nt < 2; nt++) {
            int n = (nt0 + nt) * 16 + row;
            int b = n >> 10;
            int hw = n & (HW - 1);
#pragma unroll
            for (int dc = 0; dc < 8; dc++) {
                const float* src = z + (((size_t)(b * D_DIM + dc * 32 + dq)) << 10) + hw;
                union { bf16x8 v; unsigned short u[8]; } pkk;
#pragma unroll
                for (int j = 0; j < 8; j++) pkk.u[j] = f2bf(src[(size_t)j << 10]);
                Ar[nt][dc] = pkk.v;
            }
        }
    }

    // ---- async stage of chunk 0 (16 KB = 4 x 16B per thread) ----
    {
        const unsigned int* g = (const unsigned int*)cq;
        unsigned int* l = (unsigned int*)Bbuf[0];
#pragma unroll
        for (int p = 0; p < 4; p++) {
            int off = (p * 256 + t) * 4;
            __builtin_amdgcn_global_load_lds(
                (const __attribute__((address_space(1))) unsigned int*)(g + off),
                (__attribute__((address_space(3))) unsigned int*)(l + off), 16, 0, 0);
        }
    }

    float bestd[2][4];
    int bestk[2][4];
#pragma unroll
    for (int nt = 0; nt < 2; nt++)
#pragma unroll
        for (int r = 0; r < 4; r++) { bestd[nt][r] = 3.4e38f; bestk[nt][r] = 0; }

    const int col = lane & 15;
    for (int c = 0; c < 8; c++) {
        const int cur = c & 1;
        __syncthreads();  // drains vmcnt -> Bbuf[cur] ready
        if (c < 7) {
            const unsigned int* g = (const unsigned int*)(cq + (size_t)(c + 1) * 8192);
            unsigned int* l = (unsigned int*)Bbuf[cur ^ 1];
#pragma unroll
            for (int p = 0; p < 4; p++) {
                int off = (p * 256 + t) * 4;
                __builtin_amdgcn_global_load_lds(
                    (const __attribute__((address_space(1))) unsigned int*)(g + off),
                    (__attribute__((address_space(3))) unsigned int*)(l + off), 16, 0, 0);
            }
        }
        const unsigned short* Bb = Bbuf[cur];
        bf16x8 bb[2][8];
#pragma unroll
        for (int kt2 = 0; kt2 < 2; kt2++)
#pragma unroll
            for (int dc = 0; dc < 8; dc++)
                bb[kt2][dc] = *(const bf16x8*)&Bb[((kt2 * 8 + dc) * 64 + lane) * 8];
        f32x4 acc[2][2];
#pragma unroll
        for (int nt = 0; nt < 2; nt++)
#pragma unroll
            for (int kt2 = 0; kt2 < 2; kt2++)
                acc[nt][kt2] = (f32x4){0.f, 0.f, 0.f, 0.f};
#pragma unroll
        for (int dc = 0; dc < 8; dc++)
#pragma unroll
            for (int nt = 0; nt < 2; nt++)
#pragma unroll
                for (int kt2 = 0; kt2 < 2; kt2++)
                    acc[nt][kt2] = __builtin_amdgcn_mfma_f32_16x16x32_bf16(
                        Ar[nt][dc], bb[kt2][dc], acc[nt][kt2], 0, 0, 0);
#pragma unroll
        for (int kt2 = 0; kt2 < 2; kt2++) {
            int k = (q * 16 + c * 2 + kt2) * 16 + col;
            float cn = cnorm[k];
#pragma unroll
            for (int nt = 0; nt < 2; nt++)
#pragma unroll
                for (int r = 0; r < 4; r++) {
                    float sc = fmaf(-2.0f, acc[nt][kt2][r], cn);
                    if (sc < bestd[nt][r]) { bestd[nt][r] = sc; bestk[nt][r] = k; }
                }
        }
    }

    // ---- reduce across the 16 columns; write per-quarter partials ----
#pragma unroll
    for (int nt = 0; nt < 2; nt++)
#pragma unroll
        for (int r = 0; r < 4; r++) {
            float dd = bestd[nt][r];
            int kk = bestk[nt][r];
#pragma unroll
            for (int off = 8; off >= 1; off >>= 1) {
                float d2 = __shfl_xor(dd, off);
                int k2 = __shfl_xor(kk, off);
                if (d2 < dd || (d2 == dd && k2 < kk)) { dd = d2; kk = k2; }
            }
            if ((lane & 15) == 0) {
                int n = (nt0 + nt) * 16 + (lane >> 4) * 4 + r;
                pd[q * N_VEC + n] = dd;
                pk[q * N_VEC + n] = kk;
            }
        }
}

// ---------------------------------------------------------------------------
// Kernel C: combine 4 K-quarter partials -> indices + counts histogram.
// Ascending q + strict < preserves the first-min (smallest k) tiebreak.
// ---------------------------------------------------------------------------
__global__ __launch_bounds__(256) void combine_kernel(const float* __restrict__ pd,
                                                      const int* __restrict__ pk,
                                                      int* __restrict__ indices,
                                                      int* __restrict__ counts) {
    int n = blockIdx.x * 256 + threadIdx.x;
    float best = pd[n];
    int bk = pk[n];
#pragma unroll
    for (int q = 1; q < 4; q++) {
        float d = pd[q * N_VEC + n];
        int k = pk[q * N_VEC + n];
        if (d < best) { best = d; bk = k; }
    }
    indices[n] = bk;
    atomicAdd(&counts[bk], 1);
}

// ---------------------------------------------------------------------------
// Kernel D: quantize + STE output + loss, LDS-staged codebook rows (R5-proven).
// ---------------------------------------------------------------------------
__global__ __launch_bounds__(256) void quantize_loss(const float* __restrict__ z,
                                                     const float* __restrict__ cb,
                                                     const int* __restrict__ indices,
                                                     float* __restrict__ out,
                                                     float* __restrict__ lossacc) {
    __shared__ float qs[32 * 257];
    __shared__ float wsum[4];
    const int t = threadIdx.x;
    const int lane = t & 63;
    const int w = t >> 6;
    const int n0 = blockIdx.x * 32;
    const int b = n0 >> 10;
    const int hw0 = n0 & (HW - 1);

    {
        const int rsub = lane >> 4;  // 0..3
        const int f4b = lane & 15;   // 0..15
#pragma unroll
        for (int j = 0; j < 2; j++) {
            int r = (w * 2 + j) * 4 + rsub;  // 0..31
            int code = indices[n0 + r];
            const float4* src = (const float4*)(cb + (size_t)code * D_DIM);
#pragma unroll
            for (int k = 0; k < 4; k++) {
                int f4 = f4b + 16 * k;  // 0..63
                float4 v = src[f4];
                float* dst = &qs[r * 257 + f4 * 4];
                dst[0] = v.x;
                dst[1] = v.y;
                dst[2] = v.z;
                dst[3] = v.w;
            }
        }
    }
    __syncthreads();

    const int h = lane & 31;
    const int dhalf = lane >> 5;  // 0 or 1
    float ls = 0.f;
#pragma unroll 4
    for (int i = 0; i < 32; i++) {
        int d = (i * 4 + w) * 2 + dhalf;  // 0..255
        size_t o = (((size_t)(b * D_DIM + d)) << 10) + hw0 + h;
        float q = qs[h * 257 + d];
        float zv = z[o];
        float e = q - zv;
        out[o] = zv + e;
        ls = fmaf(e, e, ls);
    }
#pragma unroll
    for (int off = 32; off >= 1; off >>= 1) ls += __shfl_down(ls, off);
    if (lane == 0) wsum[w] = ls;
    __syncthreads();
    if (t == 0) atomicAdd(lossacc, wsum[0] + wsum[1] + wsum[2] + wsum[3]);
}

// ---------------------------------------------------------------------------
// Kernel E: write one-hot encodings (fused zero + scatter; 8B-aligned stores)
// ---------------------------------------------------------------------------
__global__ __launch_bounds__(256) void write_encodings(const int* __restrict__ indices,
                                                       float* __restrict__ enc) {
    int gid = blockIdx.x * 256 + threadIdx.x;  // 0..8388607, 4 floats each
    int n = gid >> 8;
    int k0 = (gid & 255) << 2;
    int idx = indices[n];
    float2 a, b2;
    a.x = (k0 == idx) ? 1.f : 0.f;
    a.y = (k0 + 1 == idx) ? 1.f : 0.f;
    b2.x = (k0 + 2 == idx) ? 1.f : 0.f;
    b2.y = (k0 + 3 == idx) ? 1.f : 0.f;
    float* p = enc + (size_t)gid * 4;
    *(float2*)p = a;
    *(float2*)(p + 2) = b2;
}

// ---------------------------------------------------------------------------
// Kernel F: finalize loss + perplexity
// ---------------------------------------------------------------------------
__global__ __launch_bounds__(256) void finalize_kernel(const int* __restrict__ counts,
                                                       const float* __restrict__ lossacc,
                                                       float* __restrict__ out_scalars) {
    int t = threadIdx.x;
    float s = 0.f;
#pragma unroll
    for (int i = 0; i < 4; i++) {
        int k = t + i * 256;
        float p = (float)counts[k] * (1.0f / 32768.0f);
        s += p * logf(p + 1e-10f);
    }
#pragma unroll
    for (int off = 32; off >= 1; off >>= 1) s += __shfl_down(s, off);
    __shared__ float red[4];
    if ((t & 63) == 0) red[t >> 6] = s;
    __syncthreads();
    if (t == 0) {
        float tot = red[0] + red[1] + red[2] + red[3];
        out_scalars[0] = 1.25f * (lossacc[0] * (1.0f / 8388608.0f));  // q + beta*e
        out_scalars[1] = expf(-tot);                                  // perplexity
    }
}

// ---------------------------------------------------------------------------
extern "C" void kernel_launch(void* const* d_in, const int* in_sizes, int n_in,
                              void* d_out, int out_size, void* d_ws, size_t ws_size,
                              hipStream_t stream) {
    const float* z = (const float*)d_in[0];   // [32,256,32,32]
    const float* cb = (const float*)d_in[1];  // [1024,256]
    float* out = (float*)d_out;
    char* wsb = (char*)d_ws;

    float* cnorm = (float*)wsb;             // 1024 f32
    int* counts = (int*)(wsb + 4096);       // 1024 i32
    float* lossacc = (float*)(wsb + 8192);  // 1 f32
    int* indices = (int*)(wsb + 16384);     // 32768 i32

    float* quant = out;             // [0, 8388608)
    float* scal = out + N_ELEM;     // loss @ +0, perplexity @ +1
    float* enc = out + N_ELEM + 2;  // [8388610, +33554432)

    // Scratch inside the enc region of d_out (proven R5 pattern): cbb (512KB,
    // 16B-aligned), then per-quarter partials. All fully consumed by
    // combine_kernel before write_encodings overwrites the region.
    unsigned short* cbb = (unsigned short*)(out + 8388612);
    float* pd = out + 8519684;           // 4*32768 f32
    int* pk = (int*)(out + 8650756);     // 4*32768 i32

    hipLaunchKernelGGL(prep_kernel, dim3(128), dim3(256), 0, stream, cb, cbb,
                       cnorm, counts, lossacc);
    hipLaunchKernelGGL(argmin_part, dim3(1024), dim3(256), 0, stream, z, cbb,
                       cnorm, pd, pk);
    hipLaunchKernelGGL(combine_kernel, dim3(128), dim3(256), 0, stream, pd, pk,
                       indices, counts);
    hipLaunchKernelGGL(quantize_loss, dim3(1024), dim3(256), 0, stream, z, cb,
                       indices, quant, lossacc);
    hipLaunchKernelGGL(write_encodings, dim3(32768), dim3(256), 0, stream,
                       indices, enc);
    hipLaunchKernelGGL(finalize_kernel, dim3(1), dim3(256), 0, stream, counts,
                       lossacc, scal);
}

// Round 8
// 245.537 us; speedup vs baseline: 1.3705x; 1.3705x over previous
//
#include <hip/hip_runtime.h>
#include <hip/hip_bf16.h>

#define D_DIM 256
#define K_CODES 1024
#define HW 1024
#define N_VEC 32768
#define N_ELEM 8388608ull

typedef __attribute__((ext_vector_type(8))) short bf16x8;
typedef __attribute__((ext_vector_type(4))) float f32x4;

static __device__ __forceinline__ unsigned short f2bf(float x) {
    union { __hip_bfloat16 h; unsigned short u; } cvt;
    cvt.h = __float2bfloat16(x);
    return cvt.u;
}

// ---------------------------------------------------------------------------
// Kernel A (fused prep): codebook -> bf16 B-fragment order + codebook norms
// + zero counts/lossacc. 128 blocks x 256.
// ---------------------------------------------------------------------------
__global__ __launch_bounds__(256) void prep_kernel(const float* __restrict__ cb,
                                                   unsigned short* __restrict__ cbb,
                                                   float* __restrict__ cnorm,
                                                   int* __restrict__ counts,
                                                   float* __restrict__ lossacc) {
    int slot = blockIdx.x * 256 + threadIdx.x;  // 0 .. 32767
    {
        int lane = slot & 63;
        int dchunk = (slot >> 6) & 7;
        int ktile = slot >> 9;
        int code = ktile * 16 + (lane & 15);
        int d0 = dchunk * 32 + (lane >> 4) * 8;
        const float4* src = (const float4*)(cb + (size_t)code * D_DIM + d0);
        float4 v0 = src[0], v1 = src[1];
        int4 o;
        o.x = f2bf(v0.x) | ((unsigned)f2bf(v0.y) << 16);
        o.y = f2bf(v0.z) | ((unsigned)f2bf(v0.w) << 16);
        o.z = f2bf(v1.x) | ((unsigned)f2bf(v1.y) << 16);
        o.w = f2bf(v1.z) | ((unsigned)f2bf(v1.w) << 16);
        *(int4*)(cbb + (size_t)slot * 8) = o;
    }
    if (slot < 8192) {
        if (slot < K_CODES) counts[slot] = 0;
        if (slot == K_CODES) lossacc[0] = 0.f;
        int k = slot >> 3;
        int part = slot & 7;
        const float4* row = (const float4*)(cb + (size_t)k * D_DIM + part * 32);
        float s = 0.f;
#pragma unroll
        for (int i = 0; i < 8; i++) {
            float4 v = row[i];
            s = fmaf(v.x, v.x, s);
            s = fmaf(v.y, v.y, s);
            s = fmaf(v.z, v.z, s);
            s = fmaf(v.w, v.w, s);
        }
        s += __shfl_xor(s, 1);
        s += __shfl_xor(s, 2);
        s += __shfl_xor(s, 4);
        if (part == 0) cnorm[k] = s;
    }
}

// ---------------------------------------------------------------------------
// Kernel B: argmin via bf16 MFMA. Block = 512 thr (8 waves) = 128 n, with
// IN-BLOCK split-K: waves 0-3 -> codes [0,512), waves 4-7 -> [512,1024).
// 8 waves/CU (2/SIMD) doubles R5's latency hiding; z read only 2x (waves w
// and w+4 load the same A fragments), unlike R7's 4x cross-block split.
// B staged via global_load_lds(16B) double-buffer: per iteration each half
// gets 2 ktiles (16 KB); 16 iterations cover its 32 ktiles. One barrier per
// iteration (stage for c+1 issued right after the barrier). Cross-half
// combine through 2 KB LDS (R4-proven; half-0 has smaller k => strict <).
// score = ||c||^2 - 2*z.c  (per-n ||z||^2 dropped; doesn't move argmin).
// ---------------------------------------------------------------------------
__global__ __launch_bounds__(512, 2) void argmin_mfma(const float* __restrict__ z,
                                                      const unsigned short* __restrict__ cbb,
                                                      const float* __restrict__ cnorm,
                                                      int* __restrict__ indices,
                                                      int* __restrict__ counts) {
    __shared__ __align__(16) unsigned short Bbuf[2][2][8192];  // [dbuf][half][16KB]
    __shared__ float sd[128][2];
    __shared__ int sk[128][2];
    const int t = threadIdx.x;
    const int lane = t & 63;
    const int w = t >> 6;   // wave 0..7
    const int p = w & 3;    // ntile pair within block
    const int h = w >> 2;   // K-half
    const int nt0 = blockIdx.x * 8 + p * 2;

    // staging role (independent of wave's compute role): 256-thread group
    const int seg = t >> 8;   // which half's buffer this thread stages
    const int tt = t & 255;

    // ---- prologue: load + convert A fragments (2 ntiles x 8 dchunks) ----
    bf16x8 Ar[2][8];
    {
        const int row = lane & 15;
        const int dq = (lane >> 4) * 8;
#pragma unroll
        for (int nt = 0; nt < 2; nt++) {
            int n = (nt0 + nt) * 16 + row;
            int b = n >> 10;
            int hw = n & (HW - 1);
#pragma unroll
            for (int dc = 0; dc < 8; dc++) {
                const float* src = z + (((size_t)(b * D_DIM + dc * 32 + dq)) << 10) + hw;
                union { bf16x8 v; unsigned short u[8]; } pk;
#pragma unroll
                for (int j = 0; j < 8; j++) pk.u[j] = f2bf(src[(size_t)j << 10]);
                Ar[nt][dc] = pk.v;
            }
        }
    }

    // ---- async stage of iteration 0 (both halves, 32 KB total) ----
    {
        const unsigned int* g = (const unsigned int*)(cbb + (size_t)seg * 32 * 4096);
        unsigned int* l = (unsigned int*)&Bbuf[0][seg][0];
#pragma unroll
        for (int pp = 0; pp < 4; pp++) {
            int off = (pp * 256 + tt) * 4;
            __builtin_amdgcn_global_load_lds(
                (const __attribute__((address_space(1))) unsigned int*)(g + off),
                (__attribute__((address_space(3))) unsigned int*)(l + off), 16, 0, 0);
        }
    }

    float bestd[2][4];
    int bestk[2][4];
#pragma unroll
    for (int nt = 0; nt < 2; nt++)
#pragma unroll
        for (int r = 0; r < 4; r++) { bestd[nt][r] = 3.4e38f; bestk[nt][r] = 0; }

    const int col = lane & 15;
    for (int c = 0; c < 16; c++) {
        const int cur = c & 1;
        __syncthreads();  // drains vmcnt -> Bbuf[cur] ready for all waves
        if (c < 15) {
            const unsigned int* g = (const unsigned int*)
                (cbb + ((size_t)seg * 32 + (size_t)(c + 1) * 2) * 4096);
            unsigned int* l = (unsigned int*)&Bbuf[cur ^ 1][seg][0];
#pragma unroll
            for (int pp = 0; pp < 4; pp++) {
                int off = (pp * 256 + tt) * 4;
                __builtin_amdgcn_global_load_lds(
                    (const __attribute__((address_space(1))) unsigned int*)(g + off),
                    (__attribute__((address_space(3))) unsigned int*)(l + off), 16, 0, 0);
            }
        }
        const unsigned short* Bb = &Bbuf[cur][h][0];
        bf16x8 bb[2][8];
#pragma unroll
        for (int kt2 = 0; kt2 < 2; kt2++)
#pragma unroll
            for (int dc = 0; dc < 8; dc++)
                bb[kt2][dc] = *(const bf16x8*)&Bb[((kt2 * 8 + dc) * 64 + lane) * 8];
        f32x4 acc[2][2];
#pragma unroll
        for (int nt = 0; nt < 2; nt++)
#pragma unroll
            for (int kt2 = 0; kt2 < 2; kt2++)
                acc[nt][kt2] = (f32x4){0.f, 0.f, 0.f, 0.f};
#pragma unroll
        for (int dc = 0; dc < 8; dc++)
#pragma unroll
            for (int nt = 0; nt < 2; nt++)
#pragma unroll
                for (int kt2 = 0; kt2 < 2; kt2++)
                    acc[nt][kt2] = __builtin_amdgcn_mfma_f32_16x16x32_bf16(
                        Ar[nt][dc], bb[kt2][dc], acc[nt][kt2], 0, 0, 0);
#pragma unroll
        for (int kt2 = 0; kt2 < 2; kt2++) {
            int k = (h * 32 + c * 2 + kt2) * 16 + col;
            float cn = cnorm[k];
#pragma unroll
            for (int nt = 0; nt < 2; nt++)
#pragma unroll
                for (int r = 0; r < 4; r++) {
                    float sc = fmaf(-2.0f, acc[nt][kt2][r], cn);
                    if (sc < bestd[nt][r]) { bestd[nt][r] = sc; bestk[nt][r] = k; }
                }
        }
    }

    // ---- reduce across 16 columns; stash per-half result in LDS ----
#pragma unroll
    for (int nt = 0; nt < 2; nt++)
#pragma unroll
        for (int r = 0; r < 4; r++) {
            float dd = bestd[nt][r];
            int kk = bestk[nt][r];
#pragma unroll
            for (int off = 8; off >= 1; off >>= 1) {
                float d2 = __shfl_xor(dd, off);
                int k2 = __shfl_xor(kk, off);
                if (d2 < dd || (d2 == dd && k2 < kk)) { dd = d2; kk = k2; }
            }
            if ((lane & 15) == 0) {
                int nloc = (p * 2 + nt) * 16 + (lane >> 4) * 4 + r;
                sd[nloc][h] = dd;
                sk[nloc][h] = kk;
            }
        }
    __syncthreads();
    if (t < 128) {
        float d0 = sd[t][0], d1 = sd[t][1];
        int k0 = sk[t][0], k1 = sk[t][1];
        int kk = (d1 < d0) ? k1 : k0;  // half-0 has smaller k: strict <
        indices[blockIdx.x * 128 + t] = kk;
        atomicAdd(&counts[kk], 1);
    }
}

// ---------------------------------------------------------------------------
// Kernel C: quantize + STE output + loss, LDS-staged codebook rows (R5-proven).
// ---------------------------------------------------------------------------
__global__ __launch_bounds__(256) void quantize_loss(const float* __restrict__ z,
                                                     const float* __restrict__ cb,
                                                     const int* __restrict__ indices,
                                                     float* __restrict__ out,
                                                     float* __restrict__ lossacc) {
    __shared__ float qs[32 * 257];
    __shared__ float wsum[4];
    const int t = threadIdx.x;
    const int lane = t & 63;
    const int w = t >> 6;
    const int n0 = blockIdx.x * 32;
    const int b = n0 >> 10;
    const int hw0 = n0 & (HW - 1);

    {
        const int rsub = lane >> 4;  // 0..3
        const int f4b = lane & 15;   // 0..15
#pragma unroll
        for (int j = 0; j < 2; j++) {
            int r = (w * 2 + j) * 4 + rsub;  // 0..31
            int code = indices[n0 + r];
            const float4* src = (const float4*)(cb + (size_t)code * D_DIM);
#pragma unroll
            for (int k = 0; k < 4; k++) {
                int f4 = f4b + 16 * k;  // 0..63
                float4 v = src[f4];
                float* dst = &qs[r * 257 + f4 * 4];
                dst[0] = v.x;
                dst[1] = v.y;
                dst[2] = v.z;
                dst[3] = v.w;
            }
        }
    }
    __syncthreads();

    const int h = lane & 31;
    const int dhalf = lane >> 5;  // 0 or 1
    float ls = 0.f;
#pragma unroll 4
    for (int i = 0; i < 32; i++) {
        int d = (i * 4 + w) * 2 + dhalf;  // 0..255
        size_t o = (((size_t)(b * D_DIM + d)) << 10) + hw0 + h;
        float q = qs[h * 257 + d];
        float zv = z[o];
        float e = q - zv;
        out[o] = zv + e;
        ls = fmaf(e, e, ls);
    }
#pragma unroll
    for (int off = 32; off >= 1; off >>= 1) ls += __shfl_down(ls, off);
    if (lane == 0) wsum[w] = ls;
    __syncthreads();
    if (t == 0) atomicAdd(lossacc, wsum[0] + wsum[1] + wsum[2] + wsum[3]);
}

// ---------------------------------------------------------------------------
// Kernel D: write one-hot encodings (fused zero + scatter; 8B-aligned stores)
// ---------------------------------------------------------------------------
__global__ __launch_bounds__(256) void write_encodings(const int* __restrict__ indices,
                                                       float* __restrict__ enc) {
    int gid = blockIdx.x * 256 + threadIdx.x;  // 0..8388607, 4 floats each
    int n = gid >> 8;
    int k0 = (gid & 255) << 2;
    int idx = indices[n];
    float2 a, b2;
    a.x = (k0 == idx) ? 1.f : 0.f;
    a.y = (k0 + 1 == idx) ? 1.f : 0.f;
    b2.x = (k0 + 2 == idx) ? 1.f : 0.f;
    b2.y = (k0 + 3 == idx) ? 1.f : 0.f;
    float* p = enc + (size_t)gid * 4;
    *(float2*)p = a;
    *(float2*)(p + 2) = b2;
}

// ---------------------------------------------------------------------------
// Kernel E: finalize loss + perplexity
// ---------------------------------------------------------------------------
__global__ __launch_bounds__(256) void finalize_kernel(const int* __restrict__ counts,
                                                       const float* __restrict__ lossacc,
                                                       float* __restrict__ out_scalars) {
    int t = threadIdx.x;
    float s = 0.f;
#pragma unroll
    for (int i = 0; i < 4; i++) {
        int k = t + i * 256;
        float p = (float)counts[k] * (1.0f / 32768.0f);
        s += p * logf(p + 1e-10f);
    }
#pragma unroll
    for (int off = 32; off >= 1; off >>= 1) s += __shfl_down(s, off);
    __shared__ float red[4];
    if ((t & 63) == 0) red[t >> 6] = s;
    __syncthreads();
    if (t == 0) {
        float tot = red[0] + red[1] + red[2] + red[3];
        out_scalars[0] = 1.25f * (lossacc[0] * (1.0f / 8388608.0f));  // q + beta*e
        out_scalars[1] = expf(-tot);                                  // perplexity
    }
}

// ---------------------------------------------------------------------------
extern "C" void kernel_launch(void* const* d_in, const int* in_sizes, int n_in,
                              void* d_out, int out_size, void* d_ws, size_t ws_size,
                              hipStream_t stream) {
    const float* z = (const float*)d_in[0];   // [32,256,32,32]
    const float* cb = (const float*)d_in[1];  // [1024,256]
    float* out = (float*)d_out;
    char* wsb = (char*)d_ws;

    float* cnorm = (float*)wsb;             // 1024 f32
    int* counts = (int*)(wsb + 4096);       // 1024 i32
    float* lossacc = (float*)(wsb + 8192);  // 1 f32
    int* indices = (int*)(wsb + 16384);     // 32768 i32

    float* quant = out;             // [0, 8388608)
    float* scal = out + N_ELEM;     // loss @ +0, perplexity @ +1
    float* enc = out + N_ELEM + 2;  // [8388610, +33554432)

    // cbb (512KB, bf16 fragment order) lives inside the encodings region of
    // d_out; fully consumed by argmin_mfma before write_encodings overwrites.
    unsigned short* cbb = (unsigned short*)(out + 8388612);  // 16B-aligned

    hipLaunchKernelGGL(prep_kernel, dim3(128), dim3(256), 0, stream, cb, cbb,
                       cnorm, counts, lossacc);
    hipLaunchKernelGGL(argmin_mfma, dim3(256), dim3(512), 0, stream, z, cbb,
                       cnorm, indices, counts);
    hipLaunchKernelGGL(quantize_loss, dim3(1024), dim3(256), 0, stream, z, cb,
                       indices, quant, lossacc);
    hipLaunchKernelGGL(write_encodings, dim3(32768), dim3(256), 0, stream,
                       indices, enc);
    hipLaunchKernelGGL(finalize_kernel, dim3(1), dim3(256), 0, stream, counts,
                       lossacc, scal);
}